// Round 9
// baseline (650.394 us; speedup 1.0000x reference)
//
#include <hip/hip_runtime.h>

#define N_COARSE_C 250000
#define KNB 9
#define CIN 64
#define COUT 64
#define G_TILES 4         // 128-row tiles per block
#define ROWS_PER_BLOCK 512

typedef __attribute__((ext_vector_type(8))) short short8;
typedef __attribute__((ext_vector_type(4))) float f32x4;

__device__ __forceinline__ unsigned short f2bf(float x) {
    __bf16 h = (__bf16)x;                 // fptrunc = RNE; pairs fuse to v_cvt_pk_bf16_f32
    return __builtin_bit_cast(unsigned short, h);
}

// 512 threads = 8 waves; each block does 4 tiles of 128 rows (wave w owns 16).
// MFMA 16x16x32 bf16, fp32 accum. Gather pipeline is depth-2 via NAMED f32x4
// ping-pong registers (a*/b*): the WAR dep on reused names caps live pressure
// (no scratch spill — round 7's va[4][4] array was spilled) while keeping
// 8x16B loads in flight per lane. W staged once per block into LDS in
// B-fragment order -> hot-loop ds_read_b128 contiguous, conflict-free.
__global__ __launch_bounds__(512, 4) void relu_coarsen_mfma(
    const float* __restrict__ lv,      // [1e6][64] f32
    const int*   __restrict__ nbr,     // [250000][9] int32
    const float* __restrict__ W,       // [576][64] f32
    const float* __restrict__ bias,    // [64] f32
    float*       __restrict__ out)     // [250000][64] f32
{
    __shared__ short wf[18 * 4 * 64 * 8];  // 36864 bf16 = 73728 B -> 2 blocks/CU

    const int tid = threadIdx.x;

    // ---- W staging (validated round 7): vectorized loads, B-fragment layout:
    // wf[((kk*4 + (n>>4))*64 + gq*16 + (n&15))*8 + (k&7)], kk=k>>5, gq=(k>>3)&3.
    #pragma unroll
    for (int it = 0; it < 9; ++it) {
        const int q  = tid + it * 512;
        const int kp = q >> 4;            // 0..287
        const int n0 = (q & 15) * 4;      // 0,4,..,60
        const int k  = kp * 2;
        f32x4 r0 = *reinterpret_cast<const f32x4*>(W + k * 64 + n0);
        f32x4 r1 = *reinterpret_cast<const f32x4*>(W + (k + 1) * 64 + n0);
        const int kk = k >> 5;
        const int gq = (k >> 3) & 3;
        const int e  = k & 7;
        #pragma unroll
        for (int i = 0; i < 4; ++i) {
            const int n = n0 + i;
            const unsigned pk = (unsigned)f2bf(r0[i]) | ((unsigned)f2bf(r1[i]) << 16);
            const int sidx = ((kk * 4 + (n >> 4)) * 64 + gq * 16 + (n & 15)) * 8 + e;
            *reinterpret_cast<unsigned*>(&wf[sidx]) = pk;
        }
    }
    __syncthreads();

    const int lane = tid & 63;
    const int wave = tid >> 6;
    const int m    = lane & 15;   // A row within wave tile / D col
    const int g    = lane >> 4;   // k-group

    const float bv0 = bias[m], bv1 = bias[16 + m], bv2 = bias[32 + m], bv3 = bias[48 + m];

    const int block_c0 = blockIdx.x * ROWS_PER_BLOCK;

    // Issue 4 gather loads for one neighbor into named slot regs.
    // Fragment floats: kk even -> [g*8, g*8+8); kk odd -> [32+g*8, +8).
    #define GLOAD(P0, P1, P2, P3, NBJ)                                          \
    {                                                                           \
        const int rj = (NBJ);                                                   \
        const float* p = lv + (size_t)(rj < 0 ? 0 : rj) * CIN + g * 8;          \
        P0 = *reinterpret_cast<const f32x4*>(p);                                \
        P1 = *reinterpret_cast<const f32x4*>(p + 4);                            \
        P2 = *reinterpret_cast<const f32x4*>(p + 32);                           \
        P3 = *reinterpret_cast<const f32x4*>(p + 36);                           \
    }

    // Relu+cvt slot, run 8 MFMAs for neighbor J (kk = 2J, 2J+1).
    #define GMMA(P0, P1, P2, P3, NBJ, J)                                        \
    {                                                                           \
        short8 ae, ao;                                                          \
        _Pragma("unroll")                                                       \
        for (int e2 = 0; e2 < 4; ++e2) {                                        \
            ae[e2]     = (short)f2bf(fmaxf(P0[e2], 0.f));                       \
            ae[e2 + 4] = (short)f2bf(fmaxf(P1[e2], 0.f));                       \
            ao[e2]     = (short)f2bf(fmaxf(P2[e2], 0.f));                       \
            ao[e2 + 4] = (short)f2bf(fmaxf(P3[e2], 0.f));                       \
        }                                                                       \
        if ((NBJ) < 0) { ae = (short8)0; ao = (short8)0; }                      \
        _Pragma("unroll")                                                       \
        for (int nt = 0; nt < 4; ++nt) {                                        \
            const short8 be = *reinterpret_cast<const short8*>(                 \
                &wf[(((2 * (J)) * 4 + nt) * 64 + lane) * 8]);                   \
            acc[nt] = __builtin_amdgcn_mfma_f32_16x16x32_bf16(ae, be, acc[nt], 0, 0, 0); \
        }                                                                       \
        _Pragma("unroll")                                                       \
        for (int nt = 0; nt < 4; ++nt) {                                        \
            const short8 bo = *reinterpret_cast<const short8*>(                 \
                &wf[(((2 * (J) + 1) * 4 + nt) * 64 + lane) * 8]);               \
            acc[nt] = __builtin_amdgcn_mfma_f32_16x16x32_bf16(ao, bo, acc[nt], 0, 0, 0); \
        }                                                                       \
    }

    // Neighbor indices for current tile (named regs), prefetched next tile.
    int nb0, nb1, nb2, nb3, nb4, nb5, nb6, nb7, nb8;
    {
        int c = block_c0 + wave * 16 + m;
        if (c >= N_COARSE_C) c = N_COARSE_C - 1;
        const int* np = nbr + (size_t)c * KNB;
        nb0 = np[0]; nb1 = np[1]; nb2 = np[2]; nb3 = np[3]; nb4 = np[4];
        nb5 = np[5]; nb6 = np[6]; nb7 = np[7]; nb8 = np[8];
    }

    #pragma unroll 1   // one copy of the big pipelined body
    for (int t = 0; t < G_TILES; ++t) {
        const int c0 = block_c0 + t * 128 + wave * 16;

        f32x4 acc[4];
        #pragma unroll
        for (int nt = 0; nt < 4; ++nt) acc[nt] = (f32x4){0.f, 0.f, 0.f, 0.f};

        f32x4 a0, a1, a2, a3, b0, b1, b2, b3;   // ping-pong pipeline slots

        GLOAD(a0, a1, a2, a3, nb0)
        GLOAD(b0, b1, b2, b3, nb1)
        GMMA(a0, a1, a2, a3, nb0, 0) GLOAD(a0, a1, a2, a3, nb2)
        GMMA(b0, b1, b2, b3, nb1, 1) GLOAD(b0, b1, b2, b3, nb3)
        GMMA(a0, a1, a2, a3, nb2, 2) GLOAD(a0, a1, a2, a3, nb4)
        GMMA(b0, b1, b2, b3, nb3, 3) GLOAD(b0, b1, b2, b3, nb5)
        GMMA(a0, a1, a2, a3, nb4, 4) GLOAD(a0, a1, a2, a3, nb6)
        GMMA(b0, b1, b2, b3, nb5, 5) GLOAD(b0, b1, b2, b3, nb7)
        GMMA(a0, a1, a2, a3, nb6, 6) GLOAD(a0, a1, a2, a3, nb8)

        // Prefetch next tile's neighbor indices in the pipeline shadow.
        int nn0 = nb0, nn1 = nb1, nn2 = nb2, nn3 = nb3, nn4 = nb4,
            nn5 = nb5, nn6 = nb6, nn7 = nb7, nn8 = nb8;
        if (t + 1 < G_TILES) {
            int cN = block_c0 + (t + 1) * 128 + wave * 16 + m;
            if (cN >= N_COARSE_C) cN = N_COARSE_C - 1;
            const int* np = nbr + (size_t)cN * KNB;
            nn0 = np[0]; nn1 = np[1]; nn2 = np[2]; nn3 = np[3]; nn4 = np[4];
            nn5 = np[5]; nn6 = np[6]; nn7 = np[7]; nn8 = np[8];
        }

        GMMA(b0, b1, b2, b3, nb7, 7)
        GMMA(a0, a1, a2, a3, nb8, 8)

        // Epilogue: D col = lane&15 (=m), D row = g*4 + r. Add bias, store f32.
        #pragma unroll
        for (int r = 0; r < 4; ++r) {
            const int cr = c0 + g * 4 + r;
            if (cr < N_COARSE_C) {
                float* o = out + (size_t)cr * COUT + m;
                o[0]  = acc[0][r] + bv0;
                o[16] = acc[1][r] + bv1;
                o[32] = acc[2][r] + bv2;
                o[48] = acc[3][r] + bv3;
            }
        }

        nb0 = nn0; nb1 = nn1; nb2 = nn2; nb3 = nn3; nb4 = nn4;
        nb5 = nn5; nb6 = nn6; nb7 = nn7; nb8 = nn8;
    }
    #undef GLOAD
    #undef GMMA
}

extern "C" void kernel_launch(void* const* d_in, const int* in_sizes, int n_in,
                              void* d_out, int out_size, void* d_ws, size_t ws_size,
                              hipStream_t stream) {
    const float* lv   = (const float*)d_in[0];
    const int*   nbr  = (const int*)d_in[1];
    const float* W    = (const float*)d_in[2];
    const float* b    = (const float*)d_in[3];
    float* out = (float*)d_out;
    const int grid = (N_COARSE_C + ROWS_PER_BLOCK - 1) / ROWS_PER_BLOCK;  // 489
    relu_coarsen_mfma<<<grid, 512, 0, stream>>>(lv, nbr, W, b, out);
}

// Round 10
// 484.488 us; speedup vs baseline: 1.3424x; 1.3424x over previous
//
#include <hip/hip_runtime.h>

#define N_COARSE_C 250000
#define KNB 9
#define CIN 64
#define COUT 64
#define G_TILES 4         // 128-row tiles per block
#define ROWS_PER_BLOCK 512

typedef __attribute__((ext_vector_type(8))) short short8;
typedef __attribute__((ext_vector_type(4))) float f32x4;

__device__ __forceinline__ unsigned short f2bf(float x) {
    __bf16 h = (__bf16)x;                 // fptrunc = RNE; pairs fuse to v_cvt_pk_bf16_f32
    return __builtin_bit_cast(unsigned short, h);
}

// 512 threads = 8 waves; each block does 4 tiles of 128 rows (wave w owns 16).
// MFMA 16x16x32 bf16, fp32 accum. Gather pipeline depth-2 via NAMED f32x4
// ping-pong registers. __launch_bounds__(512, 2): hipcc treats arg2 as
// blocks/CU -> VGPR cap 128 (NOT 64 as with arg2=4, which forced the round-7/9
// scratch spills; occupancy is LDS-capped at 2 blocks/CU anyway).
// W staged once per block into LDS in B-fragment order -> hot-loop
// ds_read_b128 contiguous, conflict-free.
__global__ __launch_bounds__(512, 2) void relu_coarsen_mfma(
    const float* __restrict__ lv,      // [1e6][64] f32
    const int*   __restrict__ nbr,     // [250000][9] int32
    const float* __restrict__ W,       // [576][64] f32
    const float* __restrict__ bias,    // [64] f32
    float*       __restrict__ out)     // [250000][64] f32
{
    __shared__ short wf[18 * 4 * 64 * 8];  // 36864 bf16 = 73728 B -> 2 blocks/CU

    const int tid = threadIdx.x;

    // ---- W staging (validated round 7): vectorized loads, B-fragment layout:
    // wf[((kk*4 + (n>>4))*64 + gq*16 + (n&15))*8 + (k&7)], kk=k>>5, gq=(k>>3)&3.
    #pragma unroll
    for (int it = 0; it < 9; ++it) {
        const int q  = tid + it * 512;
        const int kp = q >> 4;            // 0..287
        const int n0 = (q & 15) * 4;      // 0,4,..,60
        const int k  = kp * 2;
        f32x4 r0 = *reinterpret_cast<const f32x4*>(W + k * 64 + n0);
        f32x4 r1 = *reinterpret_cast<const f32x4*>(W + (k + 1) * 64 + n0);
        const int kk = k >> 5;
        const int gq = (k >> 3) & 3;
        const int e  = k & 7;
        #pragma unroll
        for (int i = 0; i < 4; ++i) {
            const int n = n0 + i;
            const unsigned pk = (unsigned)f2bf(r0[i]) | ((unsigned)f2bf(r1[i]) << 16);
            const int sidx = ((kk * 4 + (n >> 4)) * 64 + gq * 16 + (n & 15)) * 8 + e;
            *reinterpret_cast<unsigned*>(&wf[sidx]) = pk;
        }
    }
    __syncthreads();

    const int lane = tid & 63;
    const int wave = tid >> 6;
    const int m    = lane & 15;   // A row within wave tile / D col
    const int g    = lane >> 4;   // k-group

    const float bv0 = bias[m], bv1 = bias[16 + m], bv2 = bias[32 + m], bv3 = bias[48 + m];

    const int block_c0 = blockIdx.x * ROWS_PER_BLOCK;

    // Issue 4 gather loads for one neighbor into named slot regs.
    // Fragment floats: kk even -> [g*8, g*8+8); kk odd -> [32+g*8, +8).
    #define GLOAD(P0, P1, P2, P3, NBJ)                                          \
    {                                                                           \
        const int rj = (NBJ);                                                   \
        const float* p = lv + (size_t)(rj < 0 ? 0 : rj) * CIN + g * 8;          \
        P0 = *reinterpret_cast<const f32x4*>(p);                                \
        P1 = *reinterpret_cast<const f32x4*>(p + 4);                            \
        P2 = *reinterpret_cast<const f32x4*>(p + 32);                           \
        P3 = *reinterpret_cast<const f32x4*>(p + 36);                           \
    }

    // Relu+cvt slot, run 8 MFMAs for neighbor J (kk = 2J, 2J+1).
    #define GMMA(P0, P1, P2, P3, NBJ, J)                                        \
    {                                                                           \
        short8 ae, ao;                                                          \
        _Pragma("unroll")                                                       \
        for (int e2 = 0; e2 < 4; ++e2) {                                        \
            ae[e2]     = (short)f2bf(fmaxf(P0[e2], 0.f));                       \
            ae[e2 + 4] = (short)f2bf(fmaxf(P1[e2], 0.f));                       \
            ao[e2]     = (short)f2bf(fmaxf(P2[e2], 0.f));                       \
            ao[e2 + 4] = (short)f2bf(fmaxf(P3[e2], 0.f));                       \
        }                                                                       \
        if ((NBJ) < 0) { ae = (short8)0; ao = (short8)0; }                      \
        _Pragma("unroll")                                                       \
        for (int nt = 0; nt < 4; ++nt) {                                        \
            const short8 be = *reinterpret_cast<const short8*>(                 \
                &wf[(((2 * (J)) * 4 + nt) * 64 + lane) * 8]);                   \
            acc[nt] = __builtin_amdgcn_mfma_f32_16x16x32_bf16(ae, be, acc[nt], 0, 0, 0); \
        }                                                                       \
        _Pragma("unroll")                                                       \
        for (int nt = 0; nt < 4; ++nt) {                                        \
            const short8 bo = *reinterpret_cast<const short8*>(                 \
                &wf[(((2 * (J) + 1) * 4 + nt) * 64 + lane) * 8]);               \
            acc[nt] = __builtin_amdgcn_mfma_f32_16x16x32_bf16(ao, bo, acc[nt], 0, 0, 0); \
        }                                                                       \
    }

    // Neighbor indices for current tile (named regs), prefetched next tile.
    int nb0, nb1, nb2, nb3, nb4, nb5, nb6, nb7, nb8;
    {
        int c = block_c0 + wave * 16 + m;
        if (c >= N_COARSE_C) c = N_COARSE_C - 1;
        const int* np = nbr + (size_t)c * KNB;
        nb0 = np[0]; nb1 = np[1]; nb2 = np[2]; nb3 = np[3]; nb4 = np[4];
        nb5 = np[5]; nb6 = np[6]; nb7 = np[7]; nb8 = np[8];
    }

    #pragma unroll 1   // one copy of the big pipelined body
    for (int t = 0; t < G_TILES; ++t) {
        const int c0 = block_c0 + t * 128 + wave * 16;

        f32x4 acc[4];
        #pragma unroll
        for (int nt = 0; nt < 4; ++nt) acc[nt] = (f32x4){0.f, 0.f, 0.f, 0.f};

        f32x4 a0, a1, a2, a3, b0, b1, b2, b3;   // ping-pong pipeline slots

        GLOAD(a0, a1, a2, a3, nb0)
        GLOAD(b0, b1, b2, b3, nb1)
        GMMA(a0, a1, a2, a3, nb0, 0) GLOAD(a0, a1, a2, a3, nb2)
        GMMA(b0, b1, b2, b3, nb1, 1) GLOAD(b0, b1, b2, b3, nb3)
        GMMA(a0, a1, a2, a3, nb2, 2) GLOAD(a0, a1, a2, a3, nb4)
        GMMA(b0, b1, b2, b3, nb3, 3) GLOAD(b0, b1, b2, b3, nb5)
        GMMA(a0, a1, a2, a3, nb4, 4) GLOAD(a0, a1, a2, a3, nb6)
        GMMA(b0, b1, b2, b3, nb5, 5) GLOAD(b0, b1, b2, b3, nb7)
        GMMA(a0, a1, a2, a3, nb6, 6) GLOAD(a0, a1, a2, a3, nb8)

        // Prefetch next tile's neighbor indices in the pipeline shadow.
        int nn0 = nb0, nn1 = nb1, nn2 = nb2, nn3 = nb3, nn4 = nb4,
            nn5 = nb5, nn6 = nb6, nn7 = nb7, nn8 = nb8;
        if (t + 1 < G_TILES) {
            int cN = block_c0 + (t + 1) * 128 + wave * 16 + m;
            if (cN >= N_COARSE_C) cN = N_COARSE_C - 1;
            const int* np = nbr + (size_t)cN * KNB;
            nn0 = np[0]; nn1 = np[1]; nn2 = np[2]; nn3 = np[3]; nn4 = np[4];
            nn5 = np[5]; nn6 = np[6]; nn7 = np[7]; nn8 = np[8];
        }

        GMMA(b0, b1, b2, b3, nb7, 7)
        GMMA(a0, a1, a2, a3, nb8, 8)

        // Epilogue: D col = lane&15 (=m), D row = g*4 + r. Add bias, store f32.
        #pragma unroll
        for (int r = 0; r < 4; ++r) {
            const int cr = c0 + g * 4 + r;
            if (cr < N_COARSE_C) {
                float* o = out + (size_t)cr * COUT + m;
                o[0]  = acc[0][r] + bv0;
                o[16] = acc[1][r] + bv1;
                o[32] = acc[2][r] + bv2;
                o[48] = acc[3][r] + bv3;
            }
        }

        nb0 = nn0; nb1 = nn1; nb2 = nn2; nb3 = nn3; nb4 = nn4;
        nb5 = nn5; nb6 = nn6; nb7 = nn7; nb8 = nn8;
    }
    #undef GLOAD
    #undef GMMA
}

extern "C" void kernel_launch(void* const* d_in, const int* in_sizes, int n_in,
                              void* d_out, int out_size, void* d_ws, size_t ws_size,
                              hipStream_t stream) {
    const float* lv   = (const float*)d_in[0];
    const int*   nbr  = (const int*)d_in[1];
    const float* W    = (const float*)d_in[2];
    const float* b    = (const float*)d_in[3];
    float* out = (float*)d_out;
    const int grid = (N_COARSE_C + ROWS_PER_BLOCK - 1) / ROWS_PER_BLOCK;  // 489
    relu_coarsen_mfma<<<grid, 512, 0, stream>>>(lv, nbr, W, b, out);
}